// Round 1
// baseline (2976.360 us; speedup 1.0000x reference)
//
#include <hip/hip_runtime.h>

// GINE molecule encoder, fp32 throughout.
// N=100000 nodes, E=1600000 edges, ND=64, ED=16, H=128, L=3, G=1024.

#define HCH 128      // hidden channels
#define EDIM 16      // edge feature dim
#define NLAYER 3

static __device__ __forceinline__ float4 ld4(const float* p){
  return *reinterpret_cast<const float4*>(p);
}

// ---------------------------------------------------------------------------
// CSR build: histogram -> 3-phase exclusive scan -> scatter (perm + src_perm)
// ---------------------------------------------------------------------------
__global__ void k_hist(const int* __restrict__ dst, int E, int* __restrict__ cnt){
  int j = blockIdx.x*blockDim.x + threadIdx.x;
  if (j < E) atomicAdd(&cnt[dst[j]], 1);
}

#define SC_T 256
#define SC_PER 8
#define SC_CHUNK (SC_T*SC_PER)

__global__ void k_scan1(const int* __restrict__ cnt, int N, int* __restrict__ bsum){
  __shared__ int sh[SC_T];
  int base = blockIdx.x*SC_CHUNK;
  int s = 0;
  #pragma unroll
  for (int u=0;u<SC_PER;++u){ int i = base + threadIdx.x*SC_PER + u; if (i<N) s += cnt[i]; }
  sh[threadIdx.x] = s; __syncthreads();
  for (int off=128; off>0; off>>=1){
    if (threadIdx.x < off) sh[threadIdx.x] += sh[threadIdx.x+off];
    __syncthreads();
  }
  if (threadIdx.x==0) bsum[blockIdx.x] = sh[0];
}

__global__ void k_scan2(const int* __restrict__ bsum, int NB, int* __restrict__ boff,
                        int* __restrict__ row_start, int N){
  if (threadIdx.x==0 && blockIdx.x==0){
    int run = 0;
    for (int b=0;b<NB;++b){ boff[b] = run; run += bsum[b]; }
    row_start[N] = run;   // == E
  }
}

__global__ void k_scan3(const int* __restrict__ cnt, int N, const int* __restrict__ boff,
                        int* __restrict__ row_start, int* __restrict__ cursor){
  __shared__ int sh[SC_T];
  int base = blockIdx.x*SC_CHUNK;
  int loc[SC_PER];
  int tsum = 0;
  #pragma unroll
  for (int u=0;u<SC_PER;++u){
    int i = base + threadIdx.x*SC_PER + u;
    int v = (i<N) ? cnt[i] : 0;
    loc[u] = v; tsum += v;
  }
  sh[threadIdx.x] = tsum; __syncthreads();
  for (int off=1; off<SC_T; off<<=1){
    int v = (threadIdx.x>=off) ? sh[threadIdx.x-off] : 0;
    __syncthreads();
    sh[threadIdx.x] += v;
    __syncthreads();
  }
  int run = boff[blockIdx.x] + sh[threadIdx.x] - tsum;   // exclusive prefix
  #pragma unroll
  for (int u=0;u<SC_PER;++u){
    int i = base + threadIdx.x*SC_PER + u;
    if (i<N){ row_start[i] = run; cursor[i] = run; run += loc[u]; }
  }
}

__global__ void k_scatter(const int* __restrict__ src, const int* __restrict__ dst, int E,
                          int* __restrict__ cursor, int* __restrict__ perm,
                          int* __restrict__ src_perm){
  int j = blockIdx.x*blockDim.x + threadIdx.x;
  if (j < E){
    int d = dst[j];
    int pos = atomicAdd(&cursor[d], 1);
    perm[pos] = j;
    src_perm[pos] = src[j];
  }
}

// ---------------------------------------------------------------------------
// Message + aggregate: aggr[n] = sum_{e: dst=n} relu(h[src_e] + attr_e @ edge_W + edge_b)
// One wave per destination node; lane owns 2 channels; edge_W columns in registers.
// ---------------------------------------------------------------------------
__global__ __launch_bounds__(256) void k_msg(
    const float* __restrict__ h, const float* __restrict__ edge_attr,
    const float* __restrict__ edge_W, const float* __restrict__ edge_b,
    const int* __restrict__ row_start, const int* __restrict__ perm,
    const int* __restrict__ src_perm, int N, float* __restrict__ aggr){
  int wave = threadIdx.x >> 6;
  int lane = threadIdx.x & 63;
  int n = blockIdx.x*4 + wave;
  if (n >= N) return;
  int c = lane*2;
  float w0[EDIM], w1[EDIM];
  #pragma unroll
  for (int k=0;k<EDIM;++k){
    float2 w = *reinterpret_cast<const float2*>(edge_W + k*HCH + c);
    w0[k] = w.x; w1[k] = w.y;
  }
  float2 eb = *reinterpret_cast<const float2*>(edge_b + c);
  float a0 = 0.f, a1 = 0.f;
  int e0 = row_start[n], e1 = row_start[n+1];
  for (int e = e0; e < e1; ++e){
    int j = perm[e];
    int s = src_perm[e];
    const float* ap = edge_attr + (size_t)j*EDIM;
    float4 A0 = ld4(ap), A1 = ld4(ap+4), A2 = ld4(ap+8), A3 = ld4(ap+12);
    float2 hs = *reinterpret_cast<const float2*>(h + (size_t)s*HCH + c);
    float av[EDIM] = {A0.x,A0.y,A0.z,A0.w, A1.x,A1.y,A1.z,A1.w,
                      A2.x,A2.y,A2.z,A2.w, A3.x,A3.y,A3.z,A3.w};
    float m0 = eb.x, m1 = eb.y;
    #pragma unroll
    for (int k=0;k<EDIM;++k){ m0 = fmaf(av[k], w0[k], m0); m1 = fmaf(av[k], w1[k], m1); }
    m0 = fmaxf(m0 + hs.x, 0.f);
    m1 = fmaxf(m1 + hs.y, 0.f);
    a0 += m0; a1 += m1;
  }
  *reinterpret_cast<float2*>(aggr + (size_t)n*HCH + c) = make_float2(a0, a1);
}

// ---------------------------------------------------------------------------
// Generic fp32 GEMM: C[nrows,M] = act_in(A)[nrows,K] @ W[K,M] + bias, with
// optional input transform, output relu, and fused per-column batch stats.
// Tile 128x128, 256 threads, 8x8 per thread, BK=64 chunks.
// LDS layouts chosen conflict-free (Z padded stride 65, strided row ownership).
// ---------------------------------------------------------------------------
#define TR 128
#define TCOL 128
#define BKC 64

enum { IN_PLAIN=0, IN_GINE=1, IN_BNRELU=2 };

template<int IN_MODE, bool OUT_RELU, bool STATS>
__global__ __launch_bounds__(256, 2) void k_gemm(
    const float* __restrict__ A, const float* __restrict__ A2,
    const float* __restrict__ epsp,
    const float* __restrict__ bscale, const float* __restrict__ bshift,
    const float* __restrict__ W, const float* __restrict__ bias,
    float* __restrict__ C, float* __restrict__ sums, float* __restrict__ sumsq,
    int nrows, int K, int M){
  __shared__ __align__(16) float Zl[TR][BKC+1];   // 33.3 KB
  __shared__ __align__(16) float Wl[BKC][TCOL];   // 32 KB
  int tid = threadIdx.x;
  int ty = tid >> 4, tx = tid & 15;               // thread owns rows {ty+16j}, cols {tx+16i}
  int rb = blockIdx.x * TR, cb = blockIdx.y * TCOL;
  float acc[8][8];
  #pragma unroll
  for (int j=0;j<8;++j)
    #pragma unroll
    for (int i=0;i<8;++i) acc[j][i] = 0.f;
  float epsv = 0.f;
  if (IN_MODE==IN_GINE) epsv = 1.0f + *epsp;

  for (int k0 = 0; k0 < K; k0 += BKC){
    // stage Z chunk [128 rows][64 k], row-major, padded stride 65
    #pragma unroll
    for (int t=0;t<8;++t){
      int idx = t*256 + tid;
      int f4 = idx & 15, row = idx >> 4;
      int grow = rb + row, gk = k0 + f4*4;
      float4 v = make_float4(0.f,0.f,0.f,0.f);
      if (grow < nrows){
        v = ld4(A + (size_t)grow*K + gk);
        if (IN_MODE==IN_GINE){
          float4 a2 = ld4(A2 + (size_t)grow*K + gk);
          v.x = fmaf(epsv, v.x, a2.x); v.y = fmaf(epsv, v.y, a2.y);
          v.z = fmaf(epsv, v.z, a2.z); v.w = fmaf(epsv, v.w, a2.w);
        } else if (IN_MODE==IN_BNRELU){
          float4 sc = ld4(bscale + gk), sh = ld4(bshift + gk);
          v.x = fmaxf(fmaf(v.x, sc.x, sh.x), 0.f);
          v.y = fmaxf(fmaf(v.y, sc.y, sh.y), 0.f);
          v.z = fmaxf(fmaf(v.z, sc.z, sh.z), 0.f);
          v.w = fmaxf(fmaf(v.w, sc.w, sh.w), 0.f);
        }
      }
      Zl[row][f4*4+0] = v.x; Zl[row][f4*4+1] = v.y;
      Zl[row][f4*4+2] = v.z; Zl[row][f4*4+3] = v.w;
    }
    // stage W chunk [64 k][128 cols]
    #pragma unroll
    for (int t=0;t<8;++t){
      int idx = t*256 + tid;
      int f4 = idx & 31, kk = idx >> 5;
      float4 v = ld4(W + (size_t)(k0+kk)*M + cb + f4*4);
      *reinterpret_cast<float4*>(&Wl[kk][f4*4]) = v;
    }
    __syncthreads();
    #pragma unroll 4
    for (int k=0;k<BKC;++k){
      float zr[8], wr[8];
      #pragma unroll
      for (int j=0;j<8;++j) zr[j] = Zl[ty+16*j][k];
      #pragma unroll
      for (int i=0;i<8;++i) wr[i] = Wl[k][tx+16*i];
      #pragma unroll
      for (int j=0;j<8;++j)
        #pragma unroll
        for (int i=0;i<8;++i) acc[j][i] = fmaf(zr[j], wr[i], acc[j][i]);
    }
    __syncthreads();
  }

  float bv[8];
  #pragma unroll
  for (int i=0;i<8;++i) bv[i] = bias[cb + tx + 16*i];

  float cs[8], cq[8];
  #pragma unroll
  for (int i=0;i<8;++i){ cs[i]=0.f; cq[i]=0.f; }
  #pragma unroll
  for (int j=0;j<8;++j){
    int grow = rb + ty + 16*j;
    if (grow < nrows){
      #pragma unroll
      for (int i=0;i<8;++i){
        float v = acc[j][i] + bv[i];
        if (OUT_RELU) v = fmaxf(v, 0.f);
        C[(size_t)grow*M + cb + tx + 16*i] = v;
        if (STATS){ cs[i] += v; cq[i] = fmaf(v, v, cq[i]); }
      }
    }
  }
  if (STATS){
    __syncthreads();
    float* S = &Zl[0][0];        // reuse LDS: [16][128]
    float* Q = S + 16*128;
    #pragma unroll
    for (int i=0;i<8;++i){
      S[ty*128 + tx + 16*i] = cs[i];
      Q[ty*128 + tx + 16*i] = cq[i];
    }
    __syncthreads();
    if (tid < 128){
      float s=0.f, q=0.f;
      #pragma unroll
      for (int r=0;r<16;++r){ s += S[r*128 + tid]; q += Q[r*128 + tid]; }
      atomicAdd(&sums[cb + tid], s);
      atomicAdd(&sumsq[cb + tid], q);
    }
  }
}

// ---------------------------------------------------------------------------
// BN finalize: scale/shift from sums/sumsq (biased variance, eps=1e-5)
// ---------------------------------------------------------------------------
__global__ void k_finalize(const float* __restrict__ sums, const float* __restrict__ sumsq,
                           const float* __restrict__ gamma, const float* __restrict__ beta,
                           float invN, int C, float* __restrict__ scale,
                           float* __restrict__ shift){
  int c = blockIdx.x*blockDim.x + threadIdx.x;
  if (c < C){
    float mu  = sums[c]*invN;
    float var = sumsq[c]*invN - mu*mu;
    float rstd = rsqrtf(var + 1e-5f);
    float sc = gamma[c]*rstd;
    scale[c] = sc;
    shift[c] = beta[c] - mu*sc;
  }
}

__global__ void k_bnrelu(const float* __restrict__ h2, const float* __restrict__ scale,
                         const float* __restrict__ shift, int total4, float* __restrict__ h){
  int i = blockIdx.x*blockDim.x + threadIdx.x;
  if (i < total4){
    int c4 = (i & 31)*4;                       // 128 channels / 4 per float4
    float4 v = reinterpret_cast<const float4*>(h2)[i];
    float4 sc = ld4(scale + c4), sh = ld4(shift + c4);
    v.x = fmaxf(fmaf(v.x, sc.x, sh.x), 0.f);
    v.y = fmaxf(fmaf(v.y, sc.y, sh.y), 0.f);
    v.z = fmaxf(fmaf(v.z, sc.z, sh.z), 0.f);
    v.w = fmaxf(fmaf(v.w, sc.w, sh.w), 0.f);
    reinterpret_cast<float4*>(h)[i] = v;
  }
}

// ---------------------------------------------------------------------------
// Graph boundaries (batch is sorted) + mean pool
// ---------------------------------------------------------------------------
__global__ void k_bounds(const int* __restrict__ batch, int N,
                         int* __restrict__ gstart, int* __restrict__ gend){
  int n = blockIdx.x*blockDim.x + threadIdx.x;
  if (n < N){
    int b = batch[n];
    if (n == 0) gstart[b] = 0;
    else { int pb = batch[n-1]; if (pb != b){ gstart[b] = n; gend[pb] = n; } }
    if (n == N-1) gend[b] = N;
  }
}

__global__ __launch_bounds__(128) void k_pool(const float* __restrict__ h,
                                              const int* __restrict__ gstart,
                                              const int* __restrict__ gend,
                                              float* __restrict__ pooled){
  int g = blockIdx.x, c = threadIdx.x;
  int s = gstart[g], e = gend[g];
  float acc = 0.f;
  for (int n = s; n < e; ++n) acc += h[(size_t)n*HCH + c];
  pooled[g*HCH + c] = (e > s) ? acc / (float)(e - s) : 0.f;
}

// ---------------------------------------------------------------------------
extern "C" void kernel_launch(void* const* d_in, const int* in_sizes, int n_in,
                              void* d_out, int out_size, void* d_ws, size_t ws_size,
                              hipStream_t stream){
  const float* x         = (const float*)d_in[0];
  const float* edge_attr = (const float*)d_in[1];
  const int*   edge_index= (const int*)  d_in[2];
  const int*   batch     = (const int*)  d_in[3];
  const float* node_W    = (const float*)d_in[4];
  const float* node_b    = (const float*)d_in[5];
  const float* edge_W    = (const float*)d_in[6];
  const float* edge_b    = (const float*)d_in[7];
  const float* W1s       = (const float*)d_in[8];
  const float* b1s       = (const float*)d_in[9];
  const float* g1s       = (const float*)d_in[10];
  const float* be1s      = (const float*)d_in[11];
  const float* W2s       = (const float*)d_in[12];
  const float* b2s       = (const float*)d_in[13];
  const float* epss      = (const float*)d_in[14];
  const float* bn_g      = (const float*)d_in[15];
  const float* bn_b      = (const float*)d_in[16];
  const float* ro_W1     = (const float*)d_in[17];
  const float* ro_b1     = (const float*)d_in[18];
  const float* ro_W2     = (const float*)d_in[19];
  const float* ro_b2     = (const float*)d_in[20];

  const int N = in_sizes[0] / 64;
  const int E = in_sizes[1] / EDIM;
  const int G = out_size / HCH;
  const int* src = edge_index;
  const int* dst = edge_index + E;

  char* p = (char*)d_ws;
  auto alloc = [&](size_t bytes)->char*{
    char* r = p; p += (bytes + 255) & ~(size_t)255; return r;
  };
  float* h       = (float*)alloc((size_t)N*HCH*4);
  float* aggr    = (float*)alloc((size_t)N*HCH*4);  // aliased as h2 after gemm1
  float* h2      = aggr;
  float* z1      = (float*)alloc((size_t)N*256*4);
  int*   cnt     = (int*)  alloc((size_t)N*4);
  int*   row_start=(int*)  alloc((size_t)(N+1)*4);
  int*   cursor  = (int*)  alloc((size_t)N*4);
  int*   perm    = (int*)  alloc((size_t)E*4);
  int*   src_perm= (int*)  alloc((size_t)E*4);
  int*   bsum    = (int*)  alloc(4096);
  int*   boff    = (int*)  alloc(4096);
  float* sums    = (float*)alloc(256*4);
  float* sumsq   = (float*)alloc(256*4);
  float* scale1  = (float*)alloc(256*4);
  float* shift1  = (float*)alloc(256*4);
  float* scale2  = (float*)alloc(128*4);
  float* shift2  = (float*)alloc(128*4);
  int*   gstart  = (int*)  alloc((size_t)G*4);
  int*   gend    = (int*)  alloc((size_t)G*4);
  float* pooled  = (float*)alloc((size_t)G*HCH*4);
  float* r1      = (float*)alloc((size_t)G*HCH*4);

  // ---- CSR build (once per launch) ----
  hipMemsetAsync(cnt, 0, (size_t)N*4, stream);
  k_hist<<<(E+255)/256, 256, 0, stream>>>(dst, E, cnt);
  int NB = (N + SC_CHUNK - 1)/SC_CHUNK;
  k_scan1<<<NB, SC_T, 0, stream>>>(cnt, N, bsum);
  k_scan2<<<1, 64, 0, stream>>>(bsum, NB, boff, row_start, N);
  k_scan3<<<NB, SC_T, 0, stream>>>(cnt, N, boff, row_start, cursor);
  k_scatter<<<(E+255)/256, 256, 0, stream>>>(src, dst, E, cursor, perm, src_perm);

  // ---- graph boundaries ----
  hipMemsetAsync(gstart, 0, (size_t)G*4, stream);
  hipMemsetAsync(gend,   0, (size_t)G*4, stream);
  k_bounds<<<(N+255)/256, 256, 0, stream>>>(batch, N, gstart, gend);

  // ---- node embedding: h = x @ node_W + node_b  (K=64, M=128) ----
  dim3 ge((N + TR - 1)/TR, 1);
  k_gemm<IN_PLAIN,false,false><<<ge, 256, 0, stream>>>(
      x, nullptr, nullptr, nullptr, nullptr, node_W, node_b, h,
      nullptr, nullptr, N, 64, 128);

  const float invN = 1.0f/(float)N;
  for (int l = 0; l < NLAYER; ++l){
    // aggr = sum relu(h[src] + e)
    k_msg<<<(N+3)/4, 256, 0, stream>>>(h, edge_attr, edge_W, edge_b,
                                       row_start, perm, src_perm, N, aggr);
    // z1 = ((1+eps)h + aggr) @ W1 + b1, with column stats
    hipMemsetAsync(sums,  0, 256*4, stream);
    hipMemsetAsync(sumsq, 0, 256*4, stream);
    dim3 g1((N + TR - 1)/TR, 2);
    k_gemm<IN_GINE,false,true><<<g1, 256, 0, stream>>>(
        h, aggr, epss + l, nullptr, nullptr,
        W1s + (size_t)l*128*256, b1s + (size_t)l*256, z1, sums, sumsq, N, 128, 256);
    k_finalize<<<1, 256, 0, stream>>>(sums, sumsq, g1s + (size_t)l*256,
                                      be1s + (size_t)l*256, invN, 256, scale1, shift1);
    // h2 = relu(bn(z1)) @ W2 + b2, with column stats
    hipMemsetAsync(sums,  0, 256*4, stream);
    hipMemsetAsync(sumsq, 0, 256*4, stream);
    dim3 g2((N + TR - 1)/TR, 1);
    k_gemm<IN_BNRELU,false,true><<<g2, 256, 0, stream>>>(
        z1, nullptr, nullptr, scale1, shift1,
        W2s + (size_t)l*256*128, b2s + (size_t)l*128, h2, sums, sumsq, N, 256, 128);
    k_finalize<<<1, 128, 0, stream>>>(sums, sumsq, bn_g + (size_t)l*128,
                                      bn_b + (size_t)l*128, invN, 128, scale2, shift2);
    // h = relu(bn(h2))
    int total4 = N * (HCH/4);
    k_bnrelu<<<(total4+255)/256, 256, 0, stream>>>(h2, scale2, shift2, total4, h);
  }

  // ---- mean pool + readout MLP ----
  k_pool<<<G, 128, 0, stream>>>(h, gstart, gend, pooled);
  dim3 gr((G + TR - 1)/TR, 1);
  k_gemm<IN_PLAIN,true,false><<<gr, 256, 0, stream>>>(
      pooled, nullptr, nullptr, nullptr, nullptr, ro_W1, ro_b1, r1,
      nullptr, nullptr, G, 128, 128);
  k_gemm<IN_PLAIN,false,false><<<gr, 256, 0, stream>>>(
      r1, nullptr, nullptr, nullptr, nullptr, ro_W2, ro_b2, (float*)d_out,
      nullptr, nullptr, G, 128, 128);
}

// Round 2
// 2744.510 us; speedup vs baseline: 1.0845x; 1.0845x over previous
//
#include <hip/hip_runtime.h>

// GINE molecule encoder, fp32 throughout.
// N=100000 nodes, E=1600000 edges, ND=64, ED=16, H=128, L=3, G=1024.

#define HCH 128      // hidden channels
#define EDIM 16      // edge feature dim
#define NLAYER 3

static __device__ __forceinline__ float4 ld4(const float* p){
  return *reinterpret_cast<const float4*>(p);
}

// ---------------------------------------------------------------------------
// CSR build: histogram -> 3-phase exclusive scan -> scatter (perm + src_perm)
// ---------------------------------------------------------------------------
__global__ void k_hist(const int* __restrict__ dst, int E, int* __restrict__ cnt){
  int j = blockIdx.x*blockDim.x + threadIdx.x;
  if (j < E) atomicAdd(&cnt[dst[j]], 1);
}

#define SC_T 256
#define SC_PER 8
#define SC_CHUNK (SC_T*SC_PER)

__global__ void k_scan1(const int* __restrict__ cnt, int N, int* __restrict__ bsum){
  __shared__ int sh[SC_T];
  int base = blockIdx.x*SC_CHUNK;
  int s = 0;
  #pragma unroll
  for (int u=0;u<SC_PER;++u){ int i = base + threadIdx.x*SC_PER + u; if (i<N) s += cnt[i]; }
  sh[threadIdx.x] = s; __syncthreads();
  for (int off=128; off>0; off>>=1){
    if (threadIdx.x < off) sh[threadIdx.x] += sh[threadIdx.x+off];
    __syncthreads();
  }
  if (threadIdx.x==0) bsum[blockIdx.x] = sh[0];
}

__global__ void k_scan2(const int* __restrict__ bsum, int NB, int* __restrict__ boff,
                        int* __restrict__ row_start, int N){
  if (threadIdx.x==0 && blockIdx.x==0){
    int run = 0;
    for (int b=0;b<NB;++b){ boff[b] = run; run += bsum[b]; }
    row_start[N] = run;   // == E
  }
}

__global__ void k_scan3(const int* __restrict__ cnt, int N, const int* __restrict__ boff,
                        int* __restrict__ row_start, int* __restrict__ cursor){
  __shared__ int sh[SC_T];
  int base = blockIdx.x*SC_CHUNK;
  int loc[SC_PER];
  int tsum = 0;
  #pragma unroll
  for (int u=0;u<SC_PER;++u){
    int i = base + threadIdx.x*SC_PER + u;
    int v = (i<N) ? cnt[i] : 0;
    loc[u] = v; tsum += v;
  }
  sh[threadIdx.x] = tsum; __syncthreads();
  for (int off=1; off<SC_T; off<<=1){
    int v = (threadIdx.x>=off) ? sh[threadIdx.x-off] : 0;
    __syncthreads();
    sh[threadIdx.x] += v;
    __syncthreads();
  }
  int run = boff[blockIdx.x] + sh[threadIdx.x] - tsum;   // exclusive prefix
  #pragma unroll
  for (int u=0;u<SC_PER;++u){
    int i = base + threadIdx.x*SC_PER + u;
    if (i<N){ row_start[i] = run; cursor[i] = run; run += loc[u]; }
  }
}

__global__ void k_scatter(const int* __restrict__ src, const int* __restrict__ dst, int E,
                          int* __restrict__ cursor, int* __restrict__ perm,
                          int* __restrict__ src_perm){
  int j = blockIdx.x*blockDim.x + threadIdx.x;
  if (j < E){
    int d = dst[j];
    int pos = atomicAdd(&cursor[d], 1);
    perm[pos] = j;
    src_perm[pos] = src[j];
  }
}

// Gather edge_attr rows into CSR (permuted) order: attr_p[e] = edge_attr[perm[e]]
__global__ void k_gather_attr(const int* __restrict__ perm, const float* __restrict__ edge_attr,
                              int E, float* __restrict__ attr_p){
  int t = blockIdx.x*blockDim.x + threadIdx.x;
  int e = t >> 2, f = t & 3;
  if (e < E){
    int j = perm[e];
    float4 v = ld4(edge_attr + (size_t)j*EDIM + f*4);
    *reinterpret_cast<float4*>(attr_p + (size_t)e*EDIM + f*4) = v;
  }
}

// ---------------------------------------------------------------------------
// Message + aggregate: aggr[n] = sum_{e: dst=n} relu(h[src_e] + attr_e @ edge_W + edge_b)
// One wave per destination node; lane owns 2 channels; edge_W columns in registers.
// Edge loop unrolled x2 with all loads batched ahead of compute (latency hiding).
// PRE=true: attr already permuted to CSR order (sequential stream, no perm[] indirection).
// ---------------------------------------------------------------------------
template<bool PRE>
__global__ __launch_bounds__(256) void k_msg(
    const float* __restrict__ h, const float* __restrict__ eattr,
    const int* __restrict__ perm,
    const float* __restrict__ edge_W, const float* __restrict__ edge_b,
    const int* __restrict__ row_start, const int* __restrict__ src_perm,
    int N, float* __restrict__ aggr){
  int wave = threadIdx.x >> 6;
  int lane = threadIdx.x & 63;
  int n = blockIdx.x*4 + wave;
  if (n >= N) return;
  int c = lane*2;
  float w0[EDIM], w1[EDIM];
  #pragma unroll
  for (int k=0;k<EDIM;++k){
    float2 w = *reinterpret_cast<const float2*>(edge_W + k*HCH + c);
    w0[k] = w.x; w1[k] = w.y;
  }
  float2 eb = *reinterpret_cast<const float2*>(edge_b + c);
  const float* hc = h + c;
  float a0 = 0.f, a1 = 0.f;
  int e0 = row_start[n], e1 = row_start[n+1];
  int e = e0;
  for (; e + 2 <= e1; e += 2){
    int s0 = src_perm[e], s1 = src_perm[e+1];
    const float* ap0; const float* ap1;
    if (PRE){
      ap0 = eattr + (size_t)e*EDIM; ap1 = ap0 + EDIM;
    } else {
      ap0 = eattr + (size_t)perm[e]*EDIM; ap1 = eattr + (size_t)perm[e+1]*EDIM;
    }
    float4 A0 = ld4(ap0), A1 = ld4(ap0+4), A2 = ld4(ap0+8), A3 = ld4(ap0+12);
    float4 B0 = ld4(ap1), B1 = ld4(ap1+4), B2 = ld4(ap1+8), B3 = ld4(ap1+12);
    float2 h0 = *reinterpret_cast<const float2*>(hc + (size_t)s0*HCH);
    float2 h1 = *reinterpret_cast<const float2*>(hc + (size_t)s1*HCH);
    float av[EDIM] = {A0.x,A0.y,A0.z,A0.w, A1.x,A1.y,A1.z,A1.w,
                      A2.x,A2.y,A2.z,A2.w, A3.x,A3.y,A3.z,A3.w};
    float bvv[EDIM] = {B0.x,B0.y,B0.z,B0.w, B1.x,B1.y,B1.z,B1.w,
                       B2.x,B2.y,B2.z,B2.w, B3.x,B3.y,B3.z,B3.w};
    float m0 = eb.x, m1 = eb.y, p0 = eb.x, p1 = eb.y;
    #pragma unroll
    for (int k=0;k<EDIM;++k){
      m0 = fmaf(av[k],  w0[k], m0); m1 = fmaf(av[k],  w1[k], m1);
      p0 = fmaf(bvv[k], w0[k], p0); p1 = fmaf(bvv[k], w1[k], p1);
    }
    a0 += fmaxf(m0 + h0.x, 0.f) + fmaxf(p0 + h1.x, 0.f);
    a1 += fmaxf(m1 + h0.y, 0.f) + fmaxf(p1 + h1.y, 0.f);
  }
  if (e < e1){
    int s0 = src_perm[e];
    const float* ap0 = PRE ? (eattr + (size_t)e*EDIM)
                           : (eattr + (size_t)perm[e]*EDIM);
    float4 A0 = ld4(ap0), A1 = ld4(ap0+4), A2 = ld4(ap0+8), A3 = ld4(ap0+12);
    float2 h0 = *reinterpret_cast<const float2*>(hc + (size_t)s0*HCH);
    float av[EDIM] = {A0.x,A0.y,A0.z,A0.w, A1.x,A1.y,A1.z,A1.w,
                      A2.x,A2.y,A2.z,A2.w, A3.x,A3.y,A3.z,A3.w};
    float m0 = eb.x, m1 = eb.y;
    #pragma unroll
    for (int k=0;k<EDIM;++k){ m0 = fmaf(av[k], w0[k], m0); m1 = fmaf(av[k], w1[k], m1); }
    a0 += fmaxf(m0 + h0.x, 0.f);
    a1 += fmaxf(m1 + h0.y, 0.f);
  }
  *reinterpret_cast<float2*>(aggr + (size_t)n*HCH + c) = make_float2(a0, a1);
}

// ---------------------------------------------------------------------------
// Generic fp32 GEMM: C[nrows,M] = act_in(A)[nrows,K] @ W[K,M] + bias, with
// optional input transform, output relu, and fused per-column batch stats.
// Tile 128x128, 256 threads, 8x8 per thread, BK=64 chunks.
// ---------------------------------------------------------------------------
#define TR 128
#define TCOL 128
#define BKC 64

enum { IN_PLAIN=0, IN_GINE=1, IN_BNRELU=2 };

template<int IN_MODE, bool OUT_RELU, bool STATS>
__global__ __launch_bounds__(256, 2) void k_gemm(
    const float* __restrict__ A, const float* __restrict__ A2,
    const float* __restrict__ epsp,
    const float* __restrict__ bscale, const float* __restrict__ bshift,
    const float* __restrict__ W, const float* __restrict__ bias,
    float* __restrict__ C, float* __restrict__ sums, float* __restrict__ sumsq,
    int nrows, int K, int M){
  __shared__ __align__(16) float Zl[TR][BKC+1];   // 33.3 KB
  __shared__ __align__(16) float Wl[BKC][TCOL];   // 32 KB
  int tid = threadIdx.x;
  int ty = tid >> 4, tx = tid & 15;
  int rb = blockIdx.x * TR, cb = blockIdx.y * TCOL;
  float acc[8][8];
  #pragma unroll
  for (int j=0;j<8;++j)
    #pragma unroll
    for (int i=0;i<8;++i) acc[j][i] = 0.f;
  float epsv = 0.f;
  if (IN_MODE==IN_GINE) epsv = 1.0f + *epsp;

  for (int k0 = 0; k0 < K; k0 += BKC){
    #pragma unroll
    for (int t=0;t<8;++t){
      int idx = t*256 + tid;
      int f4 = idx & 15, row = idx >> 4;
      int grow = rb + row, gk = k0 + f4*4;
      float4 v = make_float4(0.f,0.f,0.f,0.f);
      if (grow < nrows){
        v = ld4(A + (size_t)grow*K + gk);
        if (IN_MODE==IN_GINE){
          float4 a2 = ld4(A2 + (size_t)grow*K + gk);
          v.x = fmaf(epsv, v.x, a2.x); v.y = fmaf(epsv, v.y, a2.y);
          v.z = fmaf(epsv, v.z, a2.z); v.w = fmaf(epsv, v.w, a2.w);
        } else if (IN_MODE==IN_BNRELU){
          float4 sc = ld4(bscale + gk), sh = ld4(bshift + gk);
          v.x = fmaxf(fmaf(v.x, sc.x, sh.x), 0.f);
          v.y = fmaxf(fmaf(v.y, sc.y, sh.y), 0.f);
          v.z = fmaxf(fmaf(v.z, sc.z, sh.z), 0.f);
          v.w = fmaxf(fmaf(v.w, sc.w, sh.w), 0.f);
        }
      }
      Zl[row][f4*4+0] = v.x; Zl[row][f4*4+1] = v.y;
      Zl[row][f4*4+2] = v.z; Zl[row][f4*4+3] = v.w;
    }
    #pragma unroll
    for (int t=0;t<8;++t){
      int idx = t*256 + tid;
      int f4 = idx & 31, kk = idx >> 5;
      float4 v = ld4(W + (size_t)(k0+kk)*M + cb + f4*4);
      *reinterpret_cast<float4*>(&Wl[kk][f4*4]) = v;
    }
    __syncthreads();
    #pragma unroll 4
    for (int k=0;k<BKC;++k){
      float zr[8], wr[8];
      #pragma unroll
      for (int j=0;j<8;++j) zr[j] = Zl[ty+16*j][k];
      #pragma unroll
      for (int i=0;i<8;++i) wr[i] = Wl[k][tx+16*i];
      #pragma unroll
      for (int j=0;j<8;++j)
        #pragma unroll
        for (int i=0;i<8;++i) acc[j][i] = fmaf(zr[j], wr[i], acc[j][i]);
    }
    __syncthreads();
  }

  float bv[8];
  #pragma unroll
  for (int i=0;i<8;++i) bv[i] = bias[cb + tx + 16*i];

  float cs[8], cq[8];
  #pragma unroll
  for (int i=0;i<8;++i){ cs[i]=0.f; cq[i]=0.f; }
  #pragma unroll
  for (int j=0;j<8;++j){
    int grow = rb + ty + 16*j;
    if (grow < nrows){
      #pragma unroll
      for (int i=0;i<8;++i){
        float v = acc[j][i] + bv[i];
        if (OUT_RELU) v = fmaxf(v, 0.f);
        C[(size_t)grow*M + cb + tx + 16*i] = v;
        if (STATS){ cs[i] += v; cq[i] = fmaf(v, v, cq[i]); }
      }
    }
  }
  if (STATS){
    __syncthreads();
    float* S = &Zl[0][0];
    float* Q = S + 16*128;
    #pragma unroll
    for (int i=0;i<8;++i){
      S[ty*128 + tx + 16*i] = cs[i];
      Q[ty*128 + tx + 16*i] = cq[i];
    }
    __syncthreads();
    if (tid < 128){
      float s=0.f, q=0.f;
      #pragma unroll
      for (int r=0;r<16;++r){ s += S[r*128 + tid]; q += Q[r*128 + tid]; }
      atomicAdd(&sums[cb + tid], s);
      atomicAdd(&sumsq[cb + tid], q);
    }
  }
}

// ---------------------------------------------------------------------------
// BN finalize: scale/shift from sums/sumsq (biased variance, eps=1e-5)
// ---------------------------------------------------------------------------
__global__ void k_finalize(const float* __restrict__ sums, const float* __restrict__ sumsq,
                           const float* __restrict__ gamma, const float* __restrict__ beta,
                           float invN, int C, float* __restrict__ scale,
                           float* __restrict__ shift){
  int c = blockIdx.x*blockDim.x + threadIdx.x;
  if (c < C){
    float mu  = sums[c]*invN;
    float var = sumsq[c]*invN - mu*mu;
    float rstd = rsqrtf(var + 1e-5f);
    float sc = gamma[c]*rstd;
    scale[c] = sc;
    shift[c] = beta[c] - mu*sc;
  }
}

__global__ void k_bnrelu(const float* __restrict__ h2, const float* __restrict__ scale,
                         const float* __restrict__ shift, int total4, float* __restrict__ h){
  int i = blockIdx.x*blockDim.x + threadIdx.x;
  if (i < total4){
    int c4 = (i & 31)*4;
    float4 v = reinterpret_cast<const float4*>(h2)[i];
    float4 sc = ld4(scale + c4), sh = ld4(shift + c4);
    v.x = fmaxf(fmaf(v.x, sc.x, sh.x), 0.f);
    v.y = fmaxf(fmaf(v.y, sc.y, sh.y), 0.f);
    v.z = fmaxf(fmaf(v.z, sc.z, sh.z), 0.f);
    v.w = fmaxf(fmaf(v.w, sc.w, sh.w), 0.f);
    reinterpret_cast<float4*>(h)[i] = v;
  }
}

// ---------------------------------------------------------------------------
// Graph boundaries (batch is sorted) + mean pool
// ---------------------------------------------------------------------------
__global__ void k_bounds(const int* __restrict__ batch, int N,
                         int* __restrict__ gstart, int* __restrict__ gend){
  int n = blockIdx.x*blockDim.x + threadIdx.x;
  if (n < N){
    int b = batch[n];
    if (n == 0) gstart[b] = 0;
    else { int pb = batch[n-1]; if (pb != b){ gstart[b] = n; gend[pb] = n; } }
    if (n == N-1) gend[b] = N;
  }
}

__global__ __launch_bounds__(128) void k_pool(const float* __restrict__ h,
                                              const int* __restrict__ gstart,
                                              const int* __restrict__ gend,
                                              float* __restrict__ pooled){
  int g = blockIdx.x, c = threadIdx.x;
  int s = gstart[g], e = gend[g];
  float acc = 0.f;
  for (int n = s; n < e; ++n) acc += h[(size_t)n*HCH + c];
  pooled[g*HCH + c] = (e > s) ? acc / (float)(e - s) : 0.f;
}

// ---------------------------------------------------------------------------
extern "C" void kernel_launch(void* const* d_in, const int* in_sizes, int n_in,
                              void* d_out, int out_size, void* d_ws, size_t ws_size,
                              hipStream_t stream){
  const float* x         = (const float*)d_in[0];
  const float* edge_attr = (const float*)d_in[1];
  const int*   edge_index= (const int*)  d_in[2];
  const int*   batch     = (const int*)  d_in[3];
  const float* node_W    = (const float*)d_in[4];
  const float* node_b    = (const float*)d_in[5];
  const float* edge_W    = (const float*)d_in[6];
  const float* edge_b    = (const float*)d_in[7];
  const float* W1s       = (const float*)d_in[8];
  const float* b1s       = (const float*)d_in[9];
  const float* g1s       = (const float*)d_in[10];
  const float* be1s      = (const float*)d_in[11];
  const float* W2s       = (const float*)d_in[12];
  const float* b2s       = (const float*)d_in[13];
  const float* epss      = (const float*)d_in[14];
  const float* bn_g      = (const float*)d_in[15];
  const float* bn_b      = (const float*)d_in[16];
  const float* ro_W1     = (const float*)d_in[17];
  const float* ro_b1     = (const float*)d_in[18];
  const float* ro_W2     = (const float*)d_in[19];
  const float* ro_b2     = (const float*)d_in[20];

  const int N = in_sizes[0] / 64;
  const int E = in_sizes[1] / EDIM;
  const int G = out_size / HCH;
  const int* src = edge_index;
  const int* dst = edge_index + E;

  char* p = (char*)d_ws;
  auto alloc = [&](size_t bytes)->char*{
    char* r = p; p += (bytes + 255) & ~(size_t)255; return r;
  };
  float* h       = (float*)alloc((size_t)N*HCH*4);
  float* aggr    = (float*)alloc((size_t)N*HCH*4);  // aliased as h2 after gemm1
  float* h2      = aggr;
  float* z1      = (float*)alloc((size_t)N*256*4);
  int*   cnt     = (int*)  alloc((size_t)N*4);
  int*   row_start=(int*)  alloc((size_t)(N+1)*4);
  int*   cursor  = (int*)  alloc((size_t)N*4);
  int*   perm    = (int*)  alloc((size_t)E*4);
  int*   src_perm= (int*)  alloc((size_t)E*4);
  int*   bsum    = (int*)  alloc(4096);
  int*   boff    = (int*)  alloc(4096);
  float* sums    = (float*)alloc(256*4);
  float* sumsq   = (float*)alloc(256*4);
  float* scale1  = (float*)alloc(256*4);
  float* shift1  = (float*)alloc(256*4);
  float* scale2  = (float*)alloc(128*4);
  float* shift2  = (float*)alloc(128*4);
  int*   gstart  = (int*)  alloc((size_t)G*4);
  int*   gend    = (int*)  alloc((size_t)G*4);
  float* pooled  = (float*)alloc((size_t)G*HCH*4);
  float* r1      = (float*)alloc((size_t)G*HCH*4);
  // attr_p last: optional if workspace allows (102 MB)
  size_t used = (size_t)(p - (char*)d_ws);
  bool use_pre = (used + (size_t)E*EDIM*4 + 256) <= ws_size;
  float* attr_p  = use_pre ? (float*)alloc((size_t)E*EDIM*4) : nullptr;

  // ---- CSR build (once per launch) ----
  hipMemsetAsync(cnt, 0, (size_t)N*4, stream);
  k_hist<<<(E+255)/256, 256, 0, stream>>>(dst, E, cnt);
  int NB = (N + SC_CHUNK - 1)/SC_CHUNK;
  k_scan1<<<NB, SC_T, 0, stream>>>(cnt, N, bsum);
  k_scan2<<<1, 64, 0, stream>>>(bsum, NB, boff, row_start, N);
  k_scan3<<<NB, SC_T, 0, stream>>>(cnt, N, boff, row_start, cursor);
  k_scatter<<<(E+255)/256, 256, 0, stream>>>(src, dst, E, cursor, perm, src_perm);
  if (use_pre)
    k_gather_attr<<<((size_t)E*4+255)/256, 256, 0, stream>>>(perm, edge_attr, E, attr_p);

  // ---- graph boundaries ----
  hipMemsetAsync(gstart, 0, (size_t)G*4, stream);
  hipMemsetAsync(gend,   0, (size_t)G*4, stream);
  k_bounds<<<(N+255)/256, 256, 0, stream>>>(batch, N, gstart, gend);

  // ---- node embedding: h = x @ node_W + node_b  (K=64, M=128) ----
  dim3 ge((N + TR - 1)/TR, 1);
  k_gemm<IN_PLAIN,false,false><<<ge, 256, 0, stream>>>(
      x, nullptr, nullptr, nullptr, nullptr, node_W, node_b, h,
      nullptr, nullptr, N, 64, 128);

  const float invN = 1.0f/(float)N;
  for (int l = 0; l < NLAYER; ++l){
    // aggr = sum relu(h[src] + e)
    if (use_pre)
      k_msg<true><<<(N+3)/4, 256, 0, stream>>>(h, attr_p, nullptr, edge_W, edge_b,
                                               row_start, src_perm, N, aggr);
    else
      k_msg<false><<<(N+3)/4, 256, 0, stream>>>(h, edge_attr, perm, edge_W, edge_b,
                                                row_start, src_perm, N, aggr);
    // z1 = ((1+eps)h + aggr) @ W1 + b1, with column stats
    hipMemsetAsync(sums,  0, 256*4, stream);
    hipMemsetAsync(sumsq, 0, 256*4, stream);
    dim3 g1((N + TR - 1)/TR, 2);
    k_gemm<IN_GINE,false,true><<<g1, 256, 0, stream>>>(
        h, aggr, epss + l, nullptr, nullptr,
        W1s + (size_t)l*128*256, b1s + (size_t)l*256, z1, sums, sumsq, N, 128, 256);
    k_finalize<<<1, 256, 0, stream>>>(sums, sumsq, g1s + (size_t)l*256,
                                      be1s + (size_t)l*256, invN, 256, scale1, shift1);
    // h2 = relu(bn(z1)) @ W2 + b2, with column stats
    hipMemsetAsync(sums,  0, 256*4, stream);
    hipMemsetAsync(sumsq, 0, 256*4, stream);
    dim3 g2((N + TR - 1)/TR, 1);
    k_gemm<IN_BNRELU,false,true><<<g2, 256, 0, stream>>>(
        z1, nullptr, nullptr, scale1, shift1,
        W2s + (size_t)l*256*128, b2s + (size_t)l*128, h2, sums, sumsq, N, 256, 128);
    k_finalize<<<1, 128, 0, stream>>>(sums, sumsq, bn_g + (size_t)l*128,
                                      bn_b + (size_t)l*128, invN, 128, scale2, shift2);
    // h = relu(bn(h2))
    int total4 = N * (HCH/4);
    k_bnrelu<<<(total4+255)/256, 256, 0, stream>>>(h2, scale2, shift2, total4, h);
  }

  // ---- mean pool + readout MLP ----
  k_pool<<<G, 128, 0, stream>>>(h, gstart, gend, pooled);
  dim3 gr((G + TR - 1)/TR, 1);
  k_gemm<IN_PLAIN,true,false><<<gr, 256, 0, stream>>>(
      pooled, nullptr, nullptr, nullptr, nullptr, ro_W1, ro_b1, r1,
      nullptr, nullptr, G, 128, 128);
  k_gemm<IN_PLAIN,false,false><<<gr, 256, 0, stream>>>(
      r1, nullptr, nullptr, nullptr, nullptr, ro_W2, ro_b2, (float*)d_out,
      nullptr, nullptr, G, 128, 128);
}

// Round 3
// 2503.171 us; speedup vs baseline: 1.1890x; 1.0964x over previous
//
#include <hip/hip_runtime.h>

// GINE molecule encoder, fp32 throughout.
// N=100000 nodes, E=1600000 edges, ND=64, ED=16, H=128, L=3, G=1024.

#define HCH 128      // hidden channels
#define EDIM 16      // edge feature dim
#define NLAYER 3

static __device__ __forceinline__ float4 ld4(const float* p){
  return *reinterpret_cast<const float4*>(p);
}
static __device__ __forceinline__ float2 ld2(const float* p){
  return *reinterpret_cast<const float2*>(p);
}

// ---------------------------------------------------------------------------
// CSR build: histogram -> 3-phase exclusive scan -> scatter (perm + src_perm)
// ---------------------------------------------------------------------------
__global__ void k_hist(const int* __restrict__ dst, int E, int* __restrict__ cnt){
  int j = blockIdx.x*blockDim.x + threadIdx.x;
  if (j < E) atomicAdd(&cnt[dst[j]], 1);
}

#define SC_T 256
#define SC_PER 8
#define SC_CHUNK (SC_T*SC_PER)

__global__ void k_scan1(const int* __restrict__ cnt, int N, int* __restrict__ bsum){
  __shared__ int sh[SC_T];
  int base = blockIdx.x*SC_CHUNK;
  int s = 0;
  #pragma unroll
  for (int u=0;u<SC_PER;++u){ int i = base + threadIdx.x*SC_PER + u; if (i<N) s += cnt[i]; }
  sh[threadIdx.x] = s; __syncthreads();
  for (int off=128; off>0; off>>=1){
    if (threadIdx.x < off) sh[threadIdx.x] += sh[threadIdx.x+off];
    __syncthreads();
  }
  if (threadIdx.x==0) bsum[blockIdx.x] = sh[0];
}

__global__ void k_scan2(const int* __restrict__ bsum, int NB, int* __restrict__ boff,
                        int* __restrict__ row_start, int N){
  if (threadIdx.x==0 && blockIdx.x==0){
    int run = 0;
    for (int b=0;b<NB;++b){ boff[b] = run; run += bsum[b]; }
    row_start[N] = run;   // == E
  }
}

__global__ void k_scan3(const int* __restrict__ cnt, int N, const int* __restrict__ boff,
                        int* __restrict__ row_start, int* __restrict__ cursor){
  __shared__ int sh[SC_T];
  int base = blockIdx.x*SC_CHUNK;
  int loc[SC_PER];
  int tsum = 0;
  #pragma unroll
  for (int u=0;u<SC_PER;++u){
    int i = base + threadIdx.x*SC_PER + u;
    int v = (i<N) ? cnt[i] : 0;
    loc[u] = v; tsum += v;
  }
  sh[threadIdx.x] = tsum; __syncthreads();
  for (int off=1; off<SC_T; off<<=1){
    int v = (threadIdx.x>=off) ? sh[threadIdx.x-off] : 0;
    __syncthreads();
    sh[threadIdx.x] += v;
    __syncthreads();
  }
  int run = boff[blockIdx.x] + sh[threadIdx.x] - tsum;   // exclusive prefix
  #pragma unroll
  for (int u=0;u<SC_PER;++u){
    int i = base + threadIdx.x*SC_PER + u;
    if (i<N){ row_start[i] = run; cursor[i] = run; run += loc[u]; }
  }
}

__global__ void k_scatter(const int* __restrict__ src, const int* __restrict__ dst, int E,
                          int* __restrict__ cursor, int* __restrict__ perm,
                          int* __restrict__ src_perm){
  int j = blockIdx.x*blockDim.x + threadIdx.x;
  if (j < E){
    int d = dst[j];
    int pos = atomicAdd(&cursor[d], 1);
    perm[pos] = j;
    src_perm[pos] = src[j];
  }
}

// Gather edge_attr rows into CSR (permuted) order: attr_p[e] = edge_attr[perm[e]]
__global__ void k_gather_attr(const int* __restrict__ perm, const float* __restrict__ edge_attr,
                              int E, float* __restrict__ attr_p){
  int t = blockIdx.x*blockDim.x + threadIdx.x;
  int e = t >> 2, f = t & 3;
  if (e < E){
    int j = perm[e];
    float4 v = ld4(edge_attr + (size_t)j*EDIM + f*4);
    *reinterpret_cast<float4*>(attr_p + (size_t)e*EDIM + f*4) = v;
  }
}

// ---------------------------------------------------------------------------
// Message + aggregate: aggr[n] = sum_{e: dst=n} relu(h[src_e] + attr_e @ edge_W + edge_b)
// One wave per destination node; lane owns 2 channels.
// 4-edge batches, loads ordered {src x4} -> {attr x16} -> {h x4} so the edge-dot
// compute (which waits only on attr) hides the random h-gather latency.
// ---------------------------------------------------------------------------
template<bool PRE>
__global__ __launch_bounds__(256) void k_msg(
    const float* __restrict__ h, const float* __restrict__ eattr,
    const int* __restrict__ perm,
    const float* __restrict__ edge_W, const float* __restrict__ edge_b,
    const int* __restrict__ row_start, const int* __restrict__ src_perm,
    int N, float* __restrict__ aggr){
  int wave = threadIdx.x >> 6;
  int lane = threadIdx.x & 63;
  int n = blockIdx.x*4 + wave;
  if (n >= N) return;
  int c = lane*2;
  float w0[EDIM], w1[EDIM];
  #pragma unroll
  for (int k=0;k<EDIM;++k){
    float2 w = ld2(edge_W + k*HCH + c);
    w0[k] = w.x; w1[k] = w.y;
  }
  float2 eb = ld2(edge_b + c);
  const float* hc = h + c;
  float a0 = 0.f, a1 = 0.f;
  int e0 = row_start[n], e1 = row_start[n+1];

  for (int e = e0; e < e1; e += 4){
    int last = e1 - 1;
    int i1 = (e+1 < e1) ? e+1 : last;
    int i2 = (e+2 < e1) ? e+2 : last;
    int i3 = (e+3 < e1) ? e+3 : last;
    // (a) 4 independent src loads
    int s0 = src_perm[e],  s1 = src_perm[i1];
    int s2 = src_perm[i2], s3 = src_perm[i3];
    // (b) 16 sequential attr loads (4 edges x 64B)
    const float* ap0; const float* ap1; const float* ap2; const float* ap3;
    if (PRE){
      ap0 = eattr + (size_t)e *EDIM; ap1 = eattr + (size_t)i1*EDIM;
      ap2 = eattr + (size_t)i2*EDIM; ap3 = eattr + (size_t)i3*EDIM;
    } else {
      ap0 = eattr + (size_t)perm[e] *EDIM; ap1 = eattr + (size_t)perm[i1]*EDIM;
      ap2 = eattr + (size_t)perm[i2]*EDIM; ap3 = eattr + (size_t)perm[i3]*EDIM;
    }
    float4 A0 = ld4(ap0), A1 = ld4(ap0+4), A2 = ld4(ap0+8),  A3 = ld4(ap0+12);
    float4 B0 = ld4(ap1), B1 = ld4(ap1+4), B2 = ld4(ap1+8),  B3 = ld4(ap1+12);
    float4 C0 = ld4(ap2), C1 = ld4(ap2+4), C2 = ld4(ap2+8),  C3 = ld4(ap2+12);
    float4 D0 = ld4(ap3), D1 = ld4(ap3+4), D2 = ld4(ap3+8),  D3 = ld4(ap3+12);
    // (c) 4 dependent h-gather loads -- issued before the dot compute below
    float2 H0 = ld2(hc + (size_t)s0*HCH);
    float2 H1 = ld2(hc + (size_t)s1*HCH);
    float2 H2 = ld2(hc + (size_t)s2*HCH);
    float2 H3 = ld2(hc + (size_t)s3*HCH);
    // (d) edge dots: consume attr only; h loads remain in flight
    float av[EDIM] = {A0.x,A0.y,A0.z,A0.w, A1.x,A1.y,A1.z,A1.w,
                      A2.x,A2.y,A2.z,A2.w, A3.x,A3.y,A3.z,A3.w};
    float bv[EDIM] = {B0.x,B0.y,B0.z,B0.w, B1.x,B1.y,B1.z,B1.w,
                      B2.x,B2.y,B2.z,B2.w, B3.x,B3.y,B3.z,B3.w};
    float cv[EDIM] = {C0.x,C0.y,C0.z,C0.w, C1.x,C1.y,C1.z,C1.w,
                      C2.x,C2.y,C2.z,C2.w, C3.x,C3.y,C3.z,C3.w};
    float dv[EDIM] = {D0.x,D0.y,D0.z,D0.w, D1.x,D1.y,D1.z,D1.w,
                      D2.x,D2.y,D2.z,D2.w, D3.x,D3.y,D3.z,D3.w};
    float m0 = eb.x, m1 = eb.y, p0 = eb.x, p1 = eb.y;
    float q0 = eb.x, q1 = eb.y, r0 = eb.x, r1 = eb.y;
    #pragma unroll
    for (int k=0;k<EDIM;++k){
      m0 = fmaf(av[k], w0[k], m0); m1 = fmaf(av[k], w1[k], m1);
      p0 = fmaf(bv[k], w0[k], p0); p1 = fmaf(bv[k], w1[k], p1);
      q0 = fmaf(cv[k], w0[k], q0); q1 = fmaf(cv[k], w1[k], q1);
      r0 = fmaf(dv[k], w0[k], r0); r1 = fmaf(dv[k], w1[k], r1);
    }
    // (e) combine with h; masked accumulate for the clamped tail
    float v1 = (e+1 < e1) ? 1.f : 0.f;
    float v2 = (e+2 < e1) ? 1.f : 0.f;
    float v3 = (e+3 < e1) ? 1.f : 0.f;
    a0 += fmaxf(m0 + H0.x, 0.f);
    a1 += fmaxf(m1 + H0.y, 0.f);
    a0 = fmaf(v1, fmaxf(p0 + H1.x, 0.f), a0);
    a1 = fmaf(v1, fmaxf(p1 + H1.y, 0.f), a1);
    a0 = fmaf(v2, fmaxf(q0 + H2.x, 0.f), a0);
    a1 = fmaf(v2, fmaxf(q1 + H2.y, 0.f), a1);
    a0 = fmaf(v3, fmaxf(r0 + H3.x, 0.f), a0);
    a1 = fmaf(v3, fmaxf(r1 + H3.y, 0.f), a1);
  }
  *reinterpret_cast<float2*>(aggr + (size_t)n*HCH + c) = make_float2(a0, a1);
}

// ---------------------------------------------------------------------------
// Generic fp32 GEMM: C[nrows,M] = act_in(A)[nrows,K] @ W[K,M] + bias, with
// optional input transform, output relu, and fused per-column batch stats.
// Tile 128x128, 256 threads, 8x8 per thread, BK=64 chunks.
// ---------------------------------------------------------------------------
#define TR 128
#define TCOL 128
#define BKC 64

enum { IN_PLAIN=0, IN_GINE=1, IN_BNRELU=2 };

template<int IN_MODE, bool OUT_RELU, bool STATS>
__global__ __launch_bounds__(256, 2) void k_gemm(
    const float* __restrict__ A, const float* __restrict__ A2,
    const float* __restrict__ epsp,
    const float* __restrict__ bscale, const float* __restrict__ bshift,
    const float* __restrict__ W, const float* __restrict__ bias,
    float* __restrict__ C, float* __restrict__ sums, float* __restrict__ sumsq,
    int nrows, int K, int M){
  __shared__ __align__(16) float Zl[TR][BKC+1];   // 33.3 KB
  __shared__ __align__(16) float Wl[BKC][TCOL];   // 32 KB
  int tid = threadIdx.x;
  int ty = tid >> 4, tx = tid & 15;
  int rb = blockIdx.x * TR, cb = blockIdx.y * TCOL;
  float acc[8][8];
  #pragma unroll
  for (int j=0;j<8;++j)
    #pragma unroll
    for (int i=0;i<8;++i) acc[j][i] = 0.f;
  float epsv = 0.f;
  if (IN_MODE==IN_GINE) epsv = 1.0f + *epsp;

  for (int k0 = 0; k0 < K; k0 += BKC){
    #pragma unroll
    for (int t=0;t<8;++t){
      int idx = t*256 + tid;
      int f4 = idx & 15, row = idx >> 4;
      int grow = rb + row, gk = k0 + f4*4;
      float4 v = make_float4(0.f,0.f,0.f,0.f);
      if (grow < nrows){
        v = ld4(A + (size_t)grow*K + gk);
        if (IN_MODE==IN_GINE){
          float4 a2 = ld4(A2 + (size_t)grow*K + gk);
          v.x = fmaf(epsv, v.x, a2.x); v.y = fmaf(epsv, v.y, a2.y);
          v.z = fmaf(epsv, v.z, a2.z); v.w = fmaf(epsv, v.w, a2.w);
        } else if (IN_MODE==IN_BNRELU){
          float4 sc = ld4(bscale + gk), sh = ld4(bshift + gk);
          v.x = fmaxf(fmaf(v.x, sc.x, sh.x), 0.f);
          v.y = fmaxf(fmaf(v.y, sc.y, sh.y), 0.f);
          v.z = fmaxf(fmaf(v.z, sc.z, sh.z), 0.f);
          v.w = fmaxf(fmaf(v.w, sc.w, sh.w), 0.f);
        }
      }
      Zl[row][f4*4+0] = v.x; Zl[row][f4*4+1] = v.y;
      Zl[row][f4*4+2] = v.z; Zl[row][f4*4+3] = v.w;
    }
    #pragma unroll
    for (int t=0;t<8;++t){
      int idx = t*256 + tid;
      int f4 = idx & 31, kk = idx >> 5;
      float4 v = ld4(W + (size_t)(k0+kk)*M + cb + f4*4);
      *reinterpret_cast<float4*>(&Wl[kk][f4*4]) = v;
    }
    __syncthreads();
    #pragma unroll 4
    for (int k=0;k<BKC;++k){
      float zr[8], wr[8];
      #pragma unroll
      for (int j=0;j<8;++j) zr[j] = Zl[ty+16*j][k];
      #pragma unroll
      for (int i=0;i<8;++i) wr[i] = Wl[k][tx+16*i];
      #pragma unroll
      for (int j=0;j<8;++j)
        #pragma unroll
        for (int i=0;i<8;++i) acc[j][i] = fmaf(zr[j], wr[i], acc[j][i]);
    }
    __syncthreads();
  }

  float bv[8];
  #pragma unroll
  for (int i=0;i<8;++i) bv[i] = bias[cb + tx + 16*i];

  float cs[8], cq[8];
  #pragma unroll
  for (int i=0;i<8;++i){ cs[i]=0.f; cq[i]=0.f; }
  #pragma unroll
  for (int j=0;j<8;++j){
    int grow = rb + ty + 16*j;
    if (grow < nrows){
      #pragma unroll
      for (int i=0;i<8;++i){
        float v = acc[j][i] + bv[i];
        if (OUT_RELU) v = fmaxf(v, 0.f);
        C[(size_t)grow*M + cb + tx + 16*i] = v;
        if (STATS){ cs[i] += v; cq[i] = fmaf(v, v, cq[i]); }
      }
    }
  }
  if (STATS){
    __syncthreads();
    float* S = &Zl[0][0];
    float* Q = S + 16*128;
    #pragma unroll
    for (int i=0;i<8;++i){
      S[ty*128 + tx + 16*i] = cs[i];
      Q[ty*128 + tx + 16*i] = cq[i];
    }
    __syncthreads();
    if (tid < 128){
      float s=0.f, q=0.f;
      #pragma unroll
      for (int r=0;r<16;++r){ s += S[r*128 + tid]; q += Q[r*128 + tid]; }
      atomicAdd(&sums[cb + tid], s);
      atomicAdd(&sumsq[cb + tid], q);
    }
  }
}

// ---------------------------------------------------------------------------
// BN finalize: scale/shift from sums/sumsq (biased variance, eps=1e-5)
// ---------------------------------------------------------------------------
__global__ void k_finalize(const float* __restrict__ sums, const float* __restrict__ sumsq,
                           const float* __restrict__ gamma, const float* __restrict__ beta,
                           float invN, int C, float* __restrict__ scale,
                           float* __restrict__ shift){
  int c = blockIdx.x*blockDim.x + threadIdx.x;
  if (c < C){
    float mu  = sums[c]*invN;
    float var = sumsq[c]*invN - mu*mu;
    float rstd = rsqrtf(var + 1e-5f);
    float sc = gamma[c]*rstd;
    scale[c] = sc;
    shift[c] = beta[c] - mu*sc;
  }
}

__global__ void k_bnrelu(const float* __restrict__ h2, const float* __restrict__ scale,
                         const float* __restrict__ shift, int total4, float* __restrict__ h){
  int i = blockIdx.x*blockDim.x + threadIdx.x;
  if (i < total4){
    int c4 = (i & 31)*4;
    float4 v = reinterpret_cast<const float4*>(h2)[i];
    float4 sc = ld4(scale + c4), sh = ld4(shift + c4);
    v.x = fmaxf(fmaf(v.x, sc.x, sh.x), 0.f);
    v.y = fmaxf(fmaf(v.y, sc.y, sh.y), 0.f);
    v.z = fmaxf(fmaf(v.z, sc.z, sh.z), 0.f);
    v.w = fmaxf(fmaf(v.w, sc.w, sh.w), 0.f);
    reinterpret_cast<float4*>(h)[i] = v;
  }
}

// ---------------------------------------------------------------------------
// Graph boundaries (batch is sorted) + mean pool
// ---------------------------------------------------------------------------
__global__ void k_bounds(const int* __restrict__ batch, int N,
                         int* __restrict__ gstart, int* __restrict__ gend){
  int n = blockIdx.x*blockDim.x + threadIdx.x;
  if (n < N){
    int b = batch[n];
    if (n == 0) gstart[b] = 0;
    else { int pb = batch[n-1]; if (pb != b){ gstart[b] = n; gend[pb] = n; } }
    if (n == N-1) gend[b] = N;
  }
}

__global__ __launch_bounds__(128) void k_pool(const float* __restrict__ h,
                                              const int* __restrict__ gstart,
                                              const int* __restrict__ gend,
                                              float* __restrict__ pooled){
  int g = blockIdx.x, c = threadIdx.x;
  int s = gstart[g], e = gend[g];
  float acc = 0.f;
  for (int n = s; n < e; ++n) acc += h[(size_t)n*HCH + c];
  pooled[g*HCH + c] = (e > s) ? acc / (float)(e - s) : 0.f;
}

// ---------------------------------------------------------------------------
extern "C" void kernel_launch(void* const* d_in, const int* in_sizes, int n_in,
                              void* d_out, int out_size, void* d_ws, size_t ws_size,
                              hipStream_t stream){
  const float* x         = (const float*)d_in[0];
  const float* edge_attr = (const float*)d_in[1];
  const int*   edge_index= (const int*)  d_in[2];
  const int*   batch     = (const int*)  d_in[3];
  const float* node_W    = (const float*)d_in[4];
  const float* node_b    = (const float*)d_in[5];
  const float* edge_W    = (const float*)d_in[6];
  const float* edge_b    = (const float*)d_in[7];
  const float* W1s       = (const float*)d_in[8];
  const float* b1s       = (const float*)d_in[9];
  const float* g1s       = (const float*)d_in[10];
  const float* be1s      = (const float*)d_in[11];
  const float* W2s       = (const float*)d_in[12];
  const float* b2s       = (const float*)d_in[13];
  const float* epss      = (const float*)d_in[14];
  const float* bn_g      = (const float*)d_in[15];
  const float* bn_b      = (const float*)d_in[16];
  const float* ro_W1     = (const float*)d_in[17];
  const float* ro_b1     = (const float*)d_in[18];
  const float* ro_W2     = (const float*)d_in[19];
  const float* ro_b2     = (const float*)d_in[20];

  const int N = in_sizes[0] / 64;
  const int E = in_sizes[1] / EDIM;
  const int G = out_size / HCH;
  const int* src = edge_index;
  const int* dst = edge_index + E;

  char* p = (char*)d_ws;
  auto alloc = [&](size_t bytes)->char*{
    char* r = p; p += (bytes + 255) & ~(size_t)255; return r;
  };
  float* h       = (float*)alloc((size_t)N*HCH*4);
  float* aggr    = (float*)alloc((size_t)N*HCH*4);  // aliased as h2 after gemm1
  float* h2      = aggr;
  float* z1      = (float*)alloc((size_t)N*256*4);
  int*   cnt     = (int*)  alloc((size_t)N*4);
  int*   row_start=(int*)  alloc((size_t)(N+1)*4);
  int*   cursor  = (int*)  alloc((size_t)N*4);
  int*   perm    = (int*)  alloc((size_t)E*4);
  int*   src_perm= (int*)  alloc((size_t)E*4);
  int*   bsum    = (int*)  alloc(4096);
  int*   boff    = (int*)  alloc(4096);
  float* sums    = (float*)alloc(256*4);
  float* sumsq   = (float*)alloc(256*4);
  float* scale1  = (float*)alloc(256*4);
  float* shift1  = (float*)alloc(256*4);
  float* scale2  = (float*)alloc(128*4);
  float* shift2  = (float*)alloc(128*4);
  int*   gstart  = (int*)  alloc((size_t)G*4);
  int*   gend    = (int*)  alloc((size_t)G*4);
  float* pooled  = (float*)alloc((size_t)G*HCH*4);
  float* r1      = (float*)alloc((size_t)G*HCH*4);
  // attr_p last: optional if workspace allows (102 MB)
  size_t used = (size_t)(p - (char*)d_ws);
  bool use_pre = (used + (size_t)E*EDIM*4 + 256) <= ws_size;
  float* attr_p  = use_pre ? (float*)alloc((size_t)E*EDIM*4) : nullptr;

  // ---- CSR build (once per launch) ----
  hipMemsetAsync(cnt, 0, (size_t)N*4, stream);
  k_hist<<<(E+255)/256, 256, 0, stream>>>(dst, E, cnt);
  int NB = (N + SC_CHUNK - 1)/SC_CHUNK;
  k_scan1<<<NB, SC_T, 0, stream>>>(cnt, N, bsum);
  k_scan2<<<1, 64, 0, stream>>>(bsum, NB, boff, row_start, N);
  k_scan3<<<NB, SC_T, 0, stream>>>(cnt, N, boff, row_start, cursor);
  k_scatter<<<(E+255)/256, 256, 0, stream>>>(src, dst, E, cursor, perm, src_perm);
  if (use_pre)
    k_gather_attr<<<((size_t)E*4+255)/256, 256, 0, stream>>>(perm, edge_attr, E, attr_p);

  // ---- graph boundaries ----
  hipMemsetAsync(gstart, 0, (size_t)G*4, stream);
  hipMemsetAsync(gend,   0, (size_t)G*4, stream);
  k_bounds<<<(N+255)/256, 256, 0, stream>>>(batch, N, gstart, gend);

  // ---- node embedding: h = x @ node_W + node_b  (K=64, M=128) ----
  dim3 ge((N + TR - 1)/TR, 1);
  k_gemm<IN_PLAIN,false,false><<<ge, 256, 0, stream>>>(
      x, nullptr, nullptr, nullptr, nullptr, node_W, node_b, h,
      nullptr, nullptr, N, 64, 128);

  const float invN = 1.0f/(float)N;
  for (int l = 0; l < NLAYER; ++l){
    // aggr = sum relu(h[src] + e)
    if (use_pre)
      k_msg<true><<<(N+3)/4, 256, 0, stream>>>(h, attr_p, nullptr, edge_W, edge_b,
                                               row_start, src_perm, N, aggr);
    else
      k_msg<false><<<(N+3)/4, 256, 0, stream>>>(h, edge_attr, perm, edge_W, edge_b,
                                                row_start, src_perm, N, aggr);
    // z1 = ((1+eps)h + aggr) @ W1 + b1, with column stats
    hipMemsetAsync(sums,  0, 256*4, stream);
    hipMemsetAsync(sumsq, 0, 256*4, stream);
    dim3 g1((N + TR - 1)/TR, 2);
    k_gemm<IN_GINE,false,true><<<g1, 256, 0, stream>>>(
        h, aggr, epss + l, nullptr, nullptr,
        W1s + (size_t)l*128*256, b1s + (size_t)l*256, z1, sums, sumsq, N, 128, 256);
    k_finalize<<<1, 256, 0, stream>>>(sums, sumsq, g1s + (size_t)l*256,
                                      be1s + (size_t)l*256, invN, 256, scale1, shift1);
    // h2 = relu(bn(z1)) @ W2 + b2, with column stats
    hipMemsetAsync(sums,  0, 256*4, stream);
    hipMemsetAsync(sumsq, 0, 256*4, stream);
    dim3 g2((N + TR - 1)/TR, 1);
    k_gemm<IN_BNRELU,false,true><<<g2, 256, 0, stream>>>(
        z1, nullptr, nullptr, scale1, shift1,
        W2s + (size_t)l*256*128, b2s + (size_t)l*128, h2, sums, sumsq, N, 256, 128);
    k_finalize<<<1, 128, 0, stream>>>(sums, sumsq, bn_g + (size_t)l*128,
                                      bn_b + (size_t)l*128, invN, 128, scale2, shift2);
    // h = relu(bn(h2))
    int total4 = N * (HCH/4);
    k_bnrelu<<<(total4+255)/256, 256, 0, stream>>>(h2, scale2, shift2, total4, h);
  }

  // ---- mean pool + readout MLP ----
  k_pool<<<G, 128, 0, stream>>>(h, gstart, gend, pooled);
  dim3 gr((G + TR - 1)/TR, 1);
  k_gemm<IN_PLAIN,true,false><<<gr, 256, 0, stream>>>(
      pooled, nullptr, nullptr, nullptr, nullptr, ro_W1, ro_b1, r1,
      nullptr, nullptr, G, 128, 128);
  k_gemm<IN_PLAIN,false,false><<<gr, 256, 0, stream>>>(
      r1, nullptr, nullptr, nullptr, nullptr, ro_W2, ro_b2, (float*)d_out,
      nullptr, nullptr, G, 128, 128);
}